// Round 2
// baseline (139.988 us; speedup 1.0000x reference)
//
#include <hip/hip_runtime.h>

typedef __attribute__((ext_vector_type(4))) float f32x4;
typedef __attribute__((ext_vector_type(8))) short bf16x8;

__device__ __forceinline__ short f2bf(float f) {
    union { float f; unsigned u; } v; v.f = f;
    unsigned u = v.u;
    u += 0x7FFFu + ((u >> 16) & 1u);   // round-to-nearest-even
    return (short)(u >> 16);
}

// fast hw transcendentals: v_log_f32 is log2, v_exp_f32 is exp2
__device__ __forceinline__ float hw_log2(float x) { return __builtin_amdgcn_logf(x); }
__device__ __forceinline__ float hw_exp2(float x) { return __builtin_amdgcn_exp2f(x); }

// ---------------------------------------------------------------------------
// Prep: per component c (16 blocks x 64 threads):
//   b[j]   = sum_k A_c[j,k] m_c[k]
//   kscal  = m^T A m
//   biasP[c][p] = -2 b[pi(p)]         (row-permuted)
//   AbP[c][p][k] = bf16(A_c[pi(p), k]) (row-permuted, k contiguous)
// pi maps C-frag row ownership -> the k-index held in the lane's B-frag regs.
// ---------------------------------------------------------------------------
__global__ void gmm_prep(const float* __restrict__ Ainv,
                         const float* __restrict__ means,
                         short* __restrict__ AbP,
                         float* __restrict__ biasP,
                         float* __restrict__ kscal) {
    int c = blockIdx.x;
    int j = threadIdx.x;                 // 0..63, one wave
    const float* A = Ainv + c * 4096;
    const float* m = means + c * 64;
    float b = 0.f;
    #pragma unroll 8
    for (int k = 0; k < 64; ++k) b += A[j * 64 + k] * m[k];
    float km = m[j] * b;
    #pragma unroll
    for (int off = 32; off >= 1; off >>= 1) km += __shfl_xor(km, off, 64);
    if (j == 0) kscal[c] = km;

    int rt = j >> 4, qh = (j >> 2) & 3, r = j & 3;
    int pj = (rt < 2) ? (8 * qh + 4 * rt + r) : (32 + 8 * qh + 4 * (rt - 2) + r);
    biasP[c * 64 + j] = -2.0f * __shfl(b, pj, 64);

    const float* Arow = A + pj * 64;
    short* dst = AbP + c * 4096 + j * 64;
    #pragma unroll 8
    for (int k = 0; k < 64; ++k) dst[k] = f2bf(Arow[k]);
}

// ---------------------------------------------------------------------------
// Main: grid = N/128 blocks x 256 threads (4 waves x 32 samples).
// Per component: Y[(c,j), n] = A_c x  via mfma_16x16x32_bf16 (rows=perm j,
// cols=samples), acc seeded with -2b; epilogue dot with in-register fp32 x.
// ---------------------------------------------------------------------------
__global__ __launch_bounds__(256) void gmm_main(
    const float* __restrict__ X,
    const float* __restrict__ weights,
    const short* __restrict__ AbP,
    const float* __restrict__ biasP,
    const float* __restrict__ kscal,
    float* __restrict__ out) {

    __shared__ short sAb[2][64 * 72];   // padded stride 72 -> 2-way banks only
    __shared__ float sBias[16 * 64];
    __shared__ float sKW[32];           // [0..15]=k_c, [16..31]=w_c

    const int tid = threadIdx.x;
    const int lane = tid & 63;
    const int w = tid >> 6;
    const int q = lane >> 4;
    const int ln = lane & 15;

    // one-time LDS staging
    ((f32x4*)sBias)[tid] = ((const f32x4*)biasP)[tid];       // 1024 floats
    if (tid < 16) { sKW[tid] = kscal[tid]; sKW[16 + tid] = weights[tid]; }
    const int srow = tid >> 2;           // 0..63
    const int scol = (tid & 3) * 16;     // 0,16,32,48 (shorts)
    {
        const int4* src = (const int4*)(AbP + tid * 16);     // c=0 tile
        int4 a0 = src[0], a1 = src[1];
        int4* dst = (int4*)&sAb[0][srow * 72 + scol];
        dst[0] = a0; dst[1] = a1;
    }

    // x -> registers: fp32 copy (epilogue multiplier) + bf16 B-frags
    const int nbase = blockIdx.x * 128 + w * 32;
    f32x4 xv[2][2][2];                  // [t][kc][half]
    bf16x8 bfr[2][2];                   // [t][kc]
    #pragma unroll
    for (int t = 0; t < 2; ++t) {
        const float* xrow = X + (size_t)(nbase + t * 16 + ln) * 64 + q * 8;
        #pragma unroll
        for (int kc = 0; kc < 2; ++kc) {
            f32x4 xa = *(const f32x4*)(xrow + kc * 32);
            f32x4 xb = *(const f32x4*)(xrow + kc * 32 + 4);
            xv[t][kc][0] = xa; xv[t][kc][1] = xb;
            bf16x8 s;
            #pragma unroll
            for (int i = 0; i < 4; ++i) { s[i] = f2bf(xa[i]); s[4 + i] = f2bf(xb[i]); }
            bfr[t][kc] = s;
        }
    }
    __syncthreads();

    float slog[2] = {0.f, 0.f};

    for (int c = 0; c < 16; ++c) {
        const int buf = c & 1;
        int4 p0, p1;
        if (c < 15) {                    // prefetch next component (L2-hot)
            const int4* src = (const int4*)(AbP + (c + 1) * 4096 + tid * 16);
            p0 = src[0]; p1 = src[1];
        }

        bf16x8 af[4][2];
        f32x4 bias[4];
        #pragma unroll
        for (int rt = 0; rt < 4; ++rt) {
            #pragma unroll
            for (int kc = 0; kc < 2; ++kc)
                af[rt][kc] = *(const bf16x8*)&sAb[buf][(rt * 16 + ln) * 72 + kc * 32 + q * 8];
            bias[rt] = *(const f32x4*)&sBias[c * 64 + rt * 16 + q * 4];  // broadcast
        }

        #pragma unroll
        for (int t = 0; t < 2; ++t) {
            float dp = 0.f;
            #pragma unroll
            for (int rt = 0; rt < 4; ++rt) {
                f32x4 acc = __builtin_amdgcn_mfma_f32_16x16x32_bf16(
                    af[rt][0], bfr[t][0], bias[rt], 0, 0, 0);
                acc = __builtin_amdgcn_mfma_f32_16x16x32_bf16(
                    af[rt][1], bfr[t][1], acc, 0, 0, 0);
                f32x4 xm = xv[t][rt >> 1][rt & 1];   // x[n, pi(p)] in fp32
                dp += acc[0] * xm[0] + acc[1] * xm[1]
                    + acc[2] * xm[2] + acc[3] * xm[3];
            }
            dp += __shfl_xor(dp, 16, 64);
            dp += __shfl_xor(dp, 32, 64);
            float d = dp + sKW[c];
            d = fmaxf(d, 1e-30f);
            slog[t] += sKW[16 + c] * hw_log2(d);
        }

        if (c < 15) {                    // write next tile to other buffer
            int4* dst = (int4*)&sAb[buf ^ 1][srow * 72 + scol];
            dst[0] = p0; dst[1] = p1;
        }
        __syncthreads();
    }

    if (q == 0) {
        out[nbase + ln]      = hw_exp2(slog[0]);
        out[nbase + 16 + ln] = hw_exp2(slog[1]);
    }
}

extern "C" void kernel_launch(void* const* d_in, const int* in_sizes, int n_in,
                              void* d_out, int out_size, void* d_ws, size_t ws_size,
                              hipStream_t stream) {
    const float* X       = (const float*)d_in[0];
    const float* Ainv    = (const float*)d_in[1];
    const float* means   = (const float*)d_in[2];
    const float* weights = (const float*)d_in[3];
    float* out = (float*)d_out;
    const int N = in_sizes[0] / 64;

    short* AbP   = (short*)d_ws;                       // 16*64*64*2 = 131072 B
    float* biasP = (float*)((char*)d_ws + 131072);     // 4096 B
    float* kscal = (float*)((char*)d_ws + 135168);     // 64 B

    gmm_prep<<<dim3(16), dim3(64), 0, stream>>>(Ainv, means, AbP, biasP, kscal);
    gmm_main<<<dim3(N / 128), dim3(256), 0, stream>>>(X, weights, AbP, biasP, kscal, out);
}